// Round 3
// baseline (206.014 us; speedup 1.0000x reference)
//
#include <hip/hip_runtime.h>

// YOLO-v1 loss, fp32, N=16384, S=7, B=2, C=20 → 30 floats/cell, 802816 cells.
// R11 = R9 resubmitted (3rd attempt). R9 and R10 both died on
// "MI355X container failed twice" — broker/infra acquisition error, zero
// kernel-level signal (no compile, no pytest, no rocprof). Source audited:
// all accesses in-bounds, no UB, launch structure identical to R8 which ran.
// R9 theory: single-latency-window staging.
// Evidence (R8 rocprof): top-5 dispatches are ALL harness fills
// (56.2-56.5us, 6.85 TB/s writes); yolo_partial absent => kernel < 56.5us
// (>=3.4 TB/s read). Read floor is ~29us @ 6.6 TB/s for 192.7 MB.
// R4/R8 serialized TWO HBM latency windows per wave: the asm("":::"memory")
// clobber (needed for LDS-region reuse) also blocked hoisting the target
// GLOBAL loads, so each wave issued 8KB, drained vmcnt, did the LDS round
// trip, then issued the next 8KB.
// Change vs R8: pred = dense wave-contiguous dwordx4 -> wave-private LDS
// (keeps TCP request rate low); target = per-lane strided dwordx2 straight
// to VGPRs (cell*120B is 8-aligned). Both bursts issue back-to-back: ONE
// latency window, no clobber, no NT (let L2 absorb 120B-cell/128B-line
// straddle). Reduction structure bit-identical to R8 (absmax must stay 0.0).
// Predict: dur_us -> ~170 if latency-window-bound; unchanged => roofline.

typedef float vfloat4 __attribute__((ext_vector_type(4)));

constexpr int S = 7;
constexpr int FPC = 30;           // floats per cell
constexpr int BLK = 256;          // 4 waves
constexpr int WAVES = BLK / 64;
constexpr int TILE_F4 = 64 * FPC / 4;   // 480 float4 per wave tile
constexpr float STEP = 1.0f / 7.0f;
constexpr float EPS = 1e-10f;

__global__ __launch_bounds__(BLK) void yolo_partial_kernel(
    const float* __restrict__ pred,
    const float* __restrict__ target,
    float* __restrict__ partial) {
  __shared__ float lds[WAVES][64 * FPC];   // 7680 B per wave region
  __shared__ float wsum[WAVES];

  const int tid = threadIdx.x;
  const int lane = tid & 63;
  const int wid = tid >> 6;
  const int cellw = blockIdx.x * BLK + wid * 64;  // wave's first cell
  const int cell = cellw + lane;

  float* myld = lds[wid];

  // ---- burst 1: pred tile, dense 16B loads (8 per lane, wave-contiguous) ----
  vfloat4 pr[8];
  {
    const vfloat4* g = (const vfloat4*)(pred + (size_t)cellw * FPC);
    #pragma unroll
    for (int it = 0; it < 8; ++it) {
      const int idx = it * 64 + lane;
      if (idx < TILE_F4) pr[it] = g[idx];
    }
  }
  // ---- burst 2: target cell, per-lane strided 8B loads (15 per lane) ----
  float2 tv[FPC / 2];
  {
    const float2* t2 = (const float2*)(target + (size_t)cell * FPC);
    #pragma unroll
    for (int i = 0; i < FPC / 2; ++i) tv[i] = t2[i];
  }

  // ---- pred LDS round trip (wave-private region, no barrier needed) ----
  {
    vfloat4* l = (vfloat4*)myld;
    #pragma unroll
    for (int it = 0; it < 8; ++it) {
      const int idx = it * 64 + lane;
      if (idx < TILE_F4) l[idx] = pr[it];
    }
  }

  union Buf { float2 v[FPC / 2]; float f[FPC]; };
  Buf P, T;
  {
    const float2* l2 = (const float2*)(myld + lane * FPC);
    #pragma unroll
    for (int i = 0; i < FPC / 2; ++i) P.v[i] = l2[i];
  }
  #pragma unroll
  for (int i = 0; i < FPC / 2; ++i) T.v[i] = tv[i];

  const float* p = P.f;
  const float* t = T.f;

  // ---- per-cell loss (identical arithmetic to R8) ----
  const float gx = (float)(cell % S);
  const float gy = (float)((cell / S) % S);
  const float mask = (t[9] > 0.0f) ? 1.0f : 0.0f;

  float iou[2];
  #pragma unroll
  for (int b = 0; b < 2; ++b) {
    const float* pb = p + 5 * b;
    const float* tb = t + 5 * b;
    // _convert_boxes: x0=(x+gx)*STEP - w/2, clip all 4 at 0
    float px = fmaxf((pb[0] + gx) * STEP - pb[2] * 0.5f, 0.0f);
    float py = fmaxf((pb[1] + gy) * STEP - pb[3] * 0.5f, 0.0f);
    float pw = fmaxf(pb[2], 0.0f);
    float ph = fmaxf(pb[3], 0.0f);
    float tx = fmaxf((tb[0] + gx) * STEP - tb[2] * 0.5f, 0.0f);
    float ty = fmaxf((tb[1] + gy) * STEP - tb[3] * 0.5f, 0.0f);
    float tw = fmaxf(tb[2], 0.0f);
    float th = fmaxf(tb[3], 0.0f);
    float iw = fmaxf(pw + tw - (fmaxf(px + pw, tx + tw) - fminf(px, tx)), 0.0f);
    float ih = fmaxf(ph + th - (fmaxf(py + ph, ty + th) - fminf(py, ty)), 0.0f);
    float inter = iw * ih;
    float uni = pw * ph + tw * th - inter;
    iou[b] = inter / (uni + EPS);
  }
  // jnp.argmax: first max wins → box 0 on tie
  const int best = (iou[1] > iou[0]) ? 1 : 0;

  float loss = 0.0f;
  #pragma unroll
  for (int b = 0; b < 2; ++b) {
    const float* pb = p + 5 * b;
    const float* tb = t + 5 * b;
    float obj = (b == best) ? mask : 0.0f;
    float d0 = pb[0] - tb[0];
    float d1 = pb[1] - tb[1];
    float d2 = pb[2] - tb[2];
    float d3 = pb[3] - tb[3];
    loss += 5.0f * obj * (d0 * d0 + d1 * d1 + d2 * d2 + d3 * d3);  // coord
    float dc = pb[4] - iou[b];
    loss += obj * dc * dc;                                         // conf
    loss += 0.5f * (1.0f - obj) * pb[4] * pb[4];                   // noobj
  }
  float cls = 0.0f;
  #pragma unroll
  for (int k = 10; k < 30; ++k) {
    float d = p[k] - t[k];
    cls += d * d;
  }
  loss += mask * cls;                                              // class

  // ---- reduce: wave shuffle → LDS → one plain store per block ----
  #pragma unroll
  for (int off = 32; off > 0; off >>= 1)
    loss += __shfl_down(loss, off, 64);
  if ((tid & 63) == 0) wsum[wid] = loss;
  __syncthreads();
  if (tid == 0) {
    float total = 0.0f;
    #pragma unroll
    for (int w = 0; w < WAVES; ++w) total += wsum[w];
    partial[blockIdx.x] = total;          // distinct address — no atomic
  }
}

__global__ __launch_bounds__(256) void yolo_reduce_kernel(
    const float* __restrict__ partial, float* __restrict__ out,
    int n, float invN) {
  __shared__ float wsum[4];
  const int tid = threadIdx.x;
  float s = 0.0f;
  for (int i = tid; i < n; i += 256) s += partial[i];
  #pragma unroll
  for (int off = 32; off > 0; off >>= 1)
    s += __shfl_down(s, off, 64);
  if ((tid & 63) == 0) wsum[tid >> 6] = s;
  __syncthreads();
  if (tid == 0)
    out[0] = (wsum[0] + wsum[1] + wsum[2] + wsum[3]) * invN;
}

extern "C" void kernel_launch(void* const* d_in, const int* in_sizes, int n_in,
                              void* d_out, int out_size, void* d_ws, size_t ws_size,
                              hipStream_t stream) {
  const float* pred = (const float*)d_in[0];
  const float* target = (const float*)d_in[1];
  float* out = (float*)d_out;
  float* partial = (float*)d_ws;             // 3136 floats = 12.5 KB

  const int ncells = in_sizes[0] / FPC;      // 802816
  const int nblocks = ncells / BLK;          // 3136 (exact)
  const float invN = 1.0f / (float)(ncells / (S * S));  // 1/16384

  yolo_partial_kernel<<<nblocks, BLK, 0, stream>>>(pred, target, partial);
  yolo_reduce_kernel<<<1, 256, 0, stream>>>(partial, out, nblocks, invN);
}